// Round 10
// baseline (252.822 us; speedup 1.0000x reference)
//
#include <hip/hip_runtime.h>

#define CC 256
#define RC 32
#define SS 1024
#define KV 768

// ---------- K1: 2x2 pool + mix -> comb (4,256,1024) + pooled sums (no atomics) ----------
__global__ __launch_bounds__(256) void k_pool(const float* __restrict__ x,
                                              const float* __restrict__ mixp,
                                              float* __restrict__ comb,
                                              float* __restrict__ pooled) {
    int bid = blockIdx.x;
    int b = bid >> 8, c = bid & 255;
    int tid = threadIdx.x;
    int wid = tid >> 6, lane = tid & 63;
    const float* base = x + (size_t)(b * CC + c) * 4096;
    float mw = 1.f / (1.f + expf(-mixp[0]));
    float* c1 = comb + ((size_t)(b * 2 + 0) * CC + c) * SS;
    float* c2 = comb + ((size_t)(b * 2 + 1) * CC + c) * SS;
    float ls1 = 0.f, ls2 = 0.f;
    #pragma unroll
    for (int it = 0; it < 4; it++) {
        int s = tid + 256 * it;
        int oh = s >> 5, ow = s & 31;
        const float* px = base + (oh * 2) * 64 + ow * 2;
        float2 r0 = *(const float2*)px;
        float2 r1 = *(const float2*)(px + 64);
        float mx = fmaxf(fmaxf(r0.x, r0.y), fmaxf(r1.x, r1.y));
        float av = 0.25f * (r0.x + r0.y + r1.x + r1.y);
        float x1 = mx + mw * (av - mx);
        float x2 = av + mw * (mx - av);
        c1[s] = x1; c2[s] = x2;
        ls1 += x1; ls2 += x2;
    }
    #pragma unroll
    for (int off = 32; off; off >>= 1) {
        ls1 += __shfl_xor(ls1, off);
        ls2 += __shfl_xor(ls2, off);
    }
    __shared__ float sred[2][4];
    if (lane == 0) { sred[0][wid] = ls1; sred[1][wid] = ls2; }
    __syncthreads();
    if (tid == 0) {
        pooled[(b * 2 + 0) * CC + c] = sred[0][0] + sred[0][1] + sred[0][2] + sred[0][3];
        pooled[(b * 2 + 1) * CC + c] = sred[1][0] + sred[1][1] + sred[1][2] + sred[1][3];
    }
}

// ---------- K2: channel-reduce + qkv (blocks 0..255) + gate MLP (blocks 256..259) ----------
__global__ __launch_bounds__(256) void k_qkv(
        const float* __restrict__ comb, const float* __restrict__ w_red,
        const float* __restrict__ b_red, const float* __restrict__ w_qkv,
        const float* __restrict__ b_qkv,
        const float* __restrict__ pooled, const float* __restrict__ w_s1,
        const float* __restrict__ b_s1, const float* __restrict__ w_s2,
        const float* __restrict__ b_s2, float* __restrict__ gate,
        float* __restrict__ q, float* __restrict__ k, float* __restrict__ v) {
    __shared__ float wredT[CC * 33];   // [c][r], stride 33
    __shared__ float wqP[96 * 33];
    __shared__ float gred[128];
    int tid = threadIdx.x;
    if (blockIdx.x >= 256) {            // ---- gate branch (block-uniform) ----
        int b2 = blockIdx.x - 256;
        if (tid < 128) {
            const float* pl = pooled + b2 * CC;
            float acc = 0.f;
            for (int c = 0; c < CC; c++) acc += pl[c] * w_s1[tid * CC + c];
            float h1 = fmaxf(acc * (1.f / 1024.f) + b_s1[tid], 0.f);
            gred[tid] = h1 * w_s2[tid];
        }
        __syncthreads();
        if (tid < 64) gred[tid] += gred[tid + 64];
        __syncthreads();
        if (tid == 0) {
            float sum = 0.f;
            for (int i = 0; i < 64; i++) sum += gred[i];
            gate[b2] = (sum + b_s2[0] > 0.f) ? 1.f : 0.f;
        }
        return;
    }
    int b2 = blockIdx.x >> 6; int tile = blockIdx.x & 63; int s0 = tile * 16;
    for (int i = tid; i < CC * RC; i += 256) { int r = i >> 8, c = i & 255; wredT[c * 33 + r] = w_red[i]; }
    for (int i = tid; i < 96 * RC; i += 256) { int j = i >> 5, r = i & 31; wqP[j * 33 + r] = w_qkv[i]; }
    __syncthreads();
    int s_loc = tid >> 4, p = tid & 15;
    int s = s0 + s_loc;
    float xf[RC];
    #pragma unroll
    for (int r = 0; r < RC; r++) xf[r] = 0.f;
    const float* pc = comb + (size_t)(b2 * CC) * SS + s;
    #pragma unroll
    for (int ci = 0; ci < 16; ci++) {
        int c = p + 16 * ci;
        float val = pc[(size_t)c * SS];
        #pragma unroll
        for (int r = 0; r < RC; r++) xf[r] += val * wredT[c * 33 + r];
    }
    #pragma unroll
    for (int m1 = 1; m1 <= 8; m1 <<= 1) {
        #pragma unroll
        for (int r = 0; r < RC; r++) xf[r] += __shfl_xor(xf[r], m1);
    }
    #pragma unroll
    for (int r = 0; r < RC; r++) xf[r] += b_red[r];
    size_t base = (size_t)(b2 * SS + s) * RC;
    #pragma unroll
    for (int jj = 0; jj < 6; jj++) {
        int j = p * 6 + jj;
        float acc = b_qkv[j];
        #pragma unroll
        for (int r = 0; r < RC; r++) acc += xf[r] * wqP[j * 33 + r];
        if      (j < 32) q[base + j]      = acc;
        else if (j < 64) k[base + j - 32] = acc;
        else             v[base + j - 64] = acc;
    }
}

// ---------- K3: attention; 1 wave = 1 row; no LDS, no barriers; 1024 blocks ----------
// launch_bounds(256,2): VGPR cap 256 -> guaranteed no spill (round-6 lesson:
// (256,4) capped at 128 and the compiler spilled 150MB/dispatch to scratch).
__global__ __launch_bounds__(256, 2) void k_attn(
        const float* __restrict__ qg, const float* __restrict__ kg,
        const float* __restrict__ vg, float* __restrict__ mid) {
    int tid = threadIdx.x;
    int wid = tid >> 6, lane = tid & 63;
    int row = blockIdx.x * 4 + wid;               // 0..4095, same b2 within block
    int b2 = row >> 10;
    const float* kbase = kg + ((size_t)b2 << 10) * RC;
    const float* vbase = vg + ((size_t)b2 << 10) * RC;

    float qreg[RC];
    { const float4* qp = (const float4*)(qg + (size_t)row * RC);
      #pragma unroll
      for (int i = 0; i < 8; i++) { float4 t = qp[i]; qreg[4*i]=t.x; qreg[4*i+1]=t.y; qreg[4*i+2]=t.z; qreg[4*i+3]=t.w; } }

    const float scale = 0.17677669529663687f;     // 1/sqrt(32)
    unsigned int u[16];
    float lmax = -INFINITY;
    #pragma unroll
    for (int i = 0; i < 16; i++) {
        int col = lane + (i << 6);
        const float4* kr = (const float4*)(kbase + (size_t)col * RC);
        float a0 = 0.f, a1 = 0.f, a2 = 0.f, a3 = 0.f;
        #pragma unroll
        for (int j = 0; j < 8; j++) {
            float4 kv = kr[j];
            a0 += qreg[4*j] * kv.x;   a1 += qreg[4*j+1] * kv.y;
            a2 += qreg[4*j+2] * kv.z; a3 += qreg[4*j+3] * kv.w;
        }
        float d = ((a0 + a1) + (a2 + a3)) * scale;
        if (d != d) d = -INFINITY;                // NaN -> -inf per reference
        lmax = fmaxf(lmax, d);
        unsigned int bb = __float_as_uint(d);
        u[i] = bb ^ ((bb & 0x80000000u) ? 0xFFFFFFFFu : 0x80000000u);
    }
    #pragma unroll
    for (int off = 32; off; off >>= 1) lmax = fmaxf(lmax, __shfl_xor(lmax, off));
    float m = lmax;

    // ---- exact top-768 threshold: bitwise binary search on uint keys ----
    unsigned int p = 0u, utau = 0u; bool found = false;
    for (int bit = 31; bit >= 0; --bit) {
        if (found) break;
        unsigned int cand = p | (1u << bit);
        int cnt = 0;
        #pragma unroll
        for (int i = 0; i < 16; i++) cnt += (u[i] >= cand) ? 1 : 0;
        #pragma unroll
        for (int off = 1; off <= 32; off <<= 1) cnt += __shfl_xor(cnt, off);
        if (cnt >= KV) {
            if (cnt == KV) {                      // tau = min key >= cand
                unsigned int um = 0xFFFFFFFFu;
                #pragma unroll
                for (int i = 0; i < 16; i++) if (u[i] >= cand && u[i] < um) um = u[i];
                #pragma unroll
                for (int off = 1; off <= 32; off <<= 1) {
                    unsigned int o = (unsigned int)__shfl_xor((int)um, off);
                    um = (o < um) ? o : um;
                }
                utau = um; found = true;
            } else p = cand;
        }
    }
    if (!found) utau = p;

    int cg = 0, eqc = 0;
    #pragma unroll
    for (int i = 0; i < 16; i++) { cg += (u[i] > utau) ? 1 : 0; eqc += (u[i] == utau) ? 1 : 0; }
    #pragma unroll
    for (int off = 1; off <= 32; off <<= 1) { cg += __shfl_xor(cg, off); eqc += __shfl_xor(eqc, off); }
    int extra = KV - cg;

    // ---- weights overwrite keys in-place (u[i] dead after selection): saves 16 VGPRs ----
    float den = 0.f;
    if (extra == eqc) {                           // common: include all ties
        #pragma unroll
        for (int i = 0; i < 16; i++) {
            bool sel = (u[i] >= utau);
            unsigned int bb = u[i] ^ ((u[i] & 0x80000000u) ? 0x80000000u : 0xFFFFFFFFu);
            float wv = sel ? expf(__uint_as_float(bb) - m) : 0.f;
            den += wv; u[i] = __float_as_uint(wv);
        }
    } else {                                      // rare: partial ties, rank by lowest col
        int prior = 0;
        #pragma unroll
        for (int i = 0; i < 16; i++) {            // col = lane + 64*i; i-major = index order
            bool eq = (u[i] == utau);
            unsigned long long bm = __ballot(eq);
            int rank = prior + (int)__popcll(bm & ((1ull << lane) - 1ull));
            prior += (int)__popcll(bm);
            bool sel = (u[i] > utau) || (eq && rank < extra);
            unsigned int bb = u[i] ^ ((u[i] & 0x80000000u) ? 0x80000000u : 0xFFFFFFFFu);
            float wv = sel ? expf(__uint_as_float(bb) - m) : 0.f;
            den += wv; u[i] = __float_as_uint(wv);
        }
    }
    #pragma unroll
    for (int off = 1; off <= 32; off <<= 1) den += __shfl_xor(den, off);

    // ---- PV: acc[32] per lane over its 16 cols (weights read back from u) ----
    float acc[RC];
    #pragma unroll
    for (int i = 0; i < RC; i++) acc[i] = 0.f;
    #pragma unroll
    for (int i = 0; i < 16; i++) {
        int col = lane + (i << 6);
        float wj = __uint_as_float(u[i]);
        const float4* vr = (const float4*)(vbase + (size_t)col * RC);
        #pragma unroll
        for (int j = 0; j < 8; j++) {
            float4 vv = vr[j];
            acc[4*j]   += wj * vv.x; acc[4*j+1] += wj * vv.y;
            acc[4*j+2] += wj * vv.z; acc[4*j+3] += wj * vv.w;
        }
    }
    // ---- in-place register-halving butterfly: 32 regs x 64 lanes -> r = lane>>1 ----
    #pragma unroll
    for (int j = 0; j < 16; j++) {
        bool hi = (lane & 32) != 0;
        float keep = hi ? acc[j + 16] : acc[j];
        float send = hi ? acc[j] : acc[j + 16];
        acc[j] = keep + __shfl_xor(send, 32);
    }
    #pragma unroll
    for (int j = 0; j < 8; j++) {
        bool hi = (lane & 16) != 0;
        float keep = hi ? acc[j + 8] : acc[j];
        float send = hi ? acc[j] : acc[j + 8];
        acc[j] = keep + __shfl_xor(send, 16);
    }
    #pragma unroll
    for (int j = 0; j < 4; j++) {
        bool hi = (lane & 8) != 0;
        float keep = hi ? acc[j + 4] : acc[j];
        float send = hi ? acc[j] : acc[j + 4];
        acc[j] = keep + __shfl_xor(send, 8);
    }
    #pragma unroll
    for (int j = 0; j < 2; j++) {
        bool hi = (lane & 4) != 0;
        float keep = hi ? acc[j + 2] : acc[j];
        float send = hi ? acc[j] : acc[j + 2];
        acc[j] = keep + __shfl_xor(send, 4);
    }
    {
        bool hi = (lane & 2) != 0;
        float keep = hi ? acc[1] : acc[0];
        float send = hi ? acc[0] : acc[1];
        acc[0] = keep + __shfl_xor(send, 2);
    }
    float tot = acc[0] + __shfl_xor(acc[0], 1);   // lanes 2r,2r+1 hold sum for r=lane>>1
    if ((lane & 1) == 0) mid[(size_t)row * RC + (lane >> 1)] = tot / den;
}

// ---------- K4: projection 32->256 + fused out0 ----------
__global__ __launch_bounds__(256) void k_proj(
        const float* __restrict__ mid, const float* __restrict__ w_red,
        const float* __restrict__ comb, const float* __restrict__ gate,
        float* __restrict__ out0, float* __restrict__ attn_out) {
    int tid = threadIdx.x;
    // fused out0: 131072 float4s over 32768 threads
    #pragma unroll
    for (int j = 0; j < 4; j++) {
        int idx4 = blockIdx.x * 256 + tid + 32768 * j;
        int b = idx4 >> 16; int c = (idx4 >> 8) & 255; int s4 = idx4 & 255;
        const float4 v0 = *(const float4*)(comb + (((size_t)(b * 2 + 0) * CC + c) << 10) + s4 * 4);
        const float4 v1 = *(const float4*)(comb + (((size_t)(b * 2 + 1) * CC + c) << 10) + s4 * 4);
        float g0 = gate[b * 2 + 0], g1 = gate[b * 2 + 1];
        float4 o;
        o.x = fmaxf(g0 * v0.x, g1 * v1.x); o.y = fmaxf(g0 * v0.y, g1 * v1.y);
        o.z = fmaxf(g0 * v0.z, g1 * v1.z); o.w = fmaxf(g0 * v0.w, g1 * v1.w);
        *(float4*)(out0 + (size_t)idx4 * 4) = o;
    }
    __shared__ float wr[32 * 32];
    int b2 = blockIdx.x >> 5; int st = (blockIdx.x >> 3) & 3; int cch = blockIdx.x & 7;
    for (int i = tid; i < 1024; i += 256) {
        int rr = i >> 5, cc = i & 31;
        wr[i] = w_red[rr * CC + cch * 32 + cc];
    }
    __syncthreads();
    int s = st * 256 + tid;
    float xr[RC];
    const float4* mp = (const float4*)(mid + (size_t)(b2 * SS + s) * RC);
    #pragma unroll
    for (int i = 0; i < 8; i++) { float4 t4 = mp[i]; xr[4*i]=t4.x; xr[4*i+1]=t4.y; xr[4*i+2]=t4.z; xr[4*i+3]=t4.w; }
    #pragma unroll
    for (int cc = 0; cc < 32; cc++) {
        float a = 0.f;
        #pragma unroll
        for (int rr = 0; rr < RC; rr++) a += xr[rr] * wr[rr * 32 + cc];
        attn_out[((size_t)(b2 * CC) + cch * 32 + cc) * SS + s] = a;
    }
}

extern "C" void kernel_launch(void* const* d_in, const int* in_sizes, int n_in,
                              void* d_out, int out_size, void* d_ws, size_t ws_size,
                              hipStream_t stream) {
    const float* x     = (const float*)d_in[0];
    const float* mixp  = (const float*)d_in[1];
    const float* w_red = (const float*)d_in[2];
    const float* b_red = (const float*)d_in[3];
    const float* w_qkv = (const float*)d_in[4];
    const float* b_qkv = (const float*)d_in[5];
    const float* w_s1  = (const float*)d_in[6];
    const float* b_s1  = (const float*)d_in[7];
    const float* w_s2  = (const float*)d_in[8];
    const float* b_s2  = (const float*)d_in[9];
    float* out = (float*)d_out;

    float* ws     = (float*)d_ws;
    float* comb   = ws;                 // 1048576
    float* q      = comb + 1048576;     // 131072
    float* k      = q + 131072;         // 131072
    float* v      = k + 131072;         // 131072
    float* mid    = v + 131072;         // 131072
    float* pooled = mid + 131072;       // 1024
    float* gate   = pooled + 1024;      // 4

    k_pool<<<512,  256, 0, stream>>>(x, mixp, comb, pooled);
    k_qkv <<<260,  256, 0, stream>>>(comb, w_red, b_red, w_qkv, b_qkv,
                                     pooled, w_s1, b_s1, w_s2, b_s2, gate, q, k, v);
    k_attn<<<1024, 256, 0, stream>>>(q, k, v, mid);
    k_proj<<<128,  256, 0, stream>>>(mid, w_red, comb, gate, out, out + 524288);
}

// Round 11
// 155.946 us; speedup vs baseline: 1.6212x; 1.6212x over previous
//
#include <hip/hip_runtime.h>

#define CC 256
#define RC 32
#define SS 1024
#define KV 768

// ---------- K1: 2x2 pool + mix -> comb (4,256,1024) + pooled sums (no atomics) ----------
__global__ __launch_bounds__(256) void k_pool(const float* __restrict__ x,
                                              const float* __restrict__ mixp,
                                              float* __restrict__ comb,
                                              float* __restrict__ pooled) {
    int bid = blockIdx.x;
    int b = bid >> 8, c = bid & 255;
    int tid = threadIdx.x;
    int wid = tid >> 6, lane = tid & 63;
    const float* base = x + (size_t)(b * CC + c) * 4096;
    float mw = 1.f / (1.f + expf(-mixp[0]));
    float* c1 = comb + ((size_t)(b * 2 + 0) * CC + c) * SS;
    float* c2 = comb + ((size_t)(b * 2 + 1) * CC + c) * SS;
    float ls1 = 0.f, ls2 = 0.f;
    #pragma unroll
    for (int it = 0; it < 4; it++) {
        int s = tid + 256 * it;
        int oh = s >> 5, ow = s & 31;
        const float* px = base + (oh * 2) * 64 + ow * 2;
        float2 r0 = *(const float2*)px;
        float2 r1 = *(const float2*)(px + 64);
        float mx = fmaxf(fmaxf(r0.x, r0.y), fmaxf(r1.x, r1.y));
        float av = 0.25f * (r0.x + r0.y + r1.x + r1.y);
        float x1 = mx + mw * (av - mx);
        float x2 = av + mw * (mx - av);
        c1[s] = x1; c2[s] = x2;
        ls1 += x1; ls2 += x2;
    }
    #pragma unroll
    for (int off = 32; off; off >>= 1) {
        ls1 += __shfl_xor(ls1, off);
        ls2 += __shfl_xor(ls2, off);
    }
    __shared__ float sred[2][4];
    if (lane == 0) { sred[0][wid] = ls1; sred[1][wid] = ls2; }
    __syncthreads();
    if (tid == 0) {
        pooled[(b * 2 + 0) * CC + c] = sred[0][0] + sred[0][1] + sred[0][2] + sred[0][3];
        pooled[(b * 2 + 1) * CC + c] = sred[1][0] + sred[1][1] + sred[1][2] + sred[1][3];
    }
}

// ---------- K2: channel-reduce + qkv (blocks 0..255, K/V transposed) + gate MLP ----------
__global__ __launch_bounds__(256) void k_qkv(
        const float* __restrict__ comb, const float* __restrict__ w_red,
        const float* __restrict__ b_red, const float* __restrict__ w_qkv,
        const float* __restrict__ b_qkv,
        const float* __restrict__ pooled, const float* __restrict__ w_s1,
        const float* __restrict__ b_s1, const float* __restrict__ w_s2,
        const float* __restrict__ b_s2, float* __restrict__ gate,
        float* __restrict__ q, float* __restrict__ kT, float* __restrict__ vT) {
    __shared__ float wredT[CC * 33];   // [c][r], stride 33
    __shared__ float wqP[96 * 33];
    __shared__ float gred[128];
    int tid = threadIdx.x;
    if (blockIdx.x >= 256) {            // ---- gate branch (block-uniform) ----
        int b2 = blockIdx.x - 256;
        if (tid < 128) {
            const float* pl = pooled + b2 * CC;
            float acc = 0.f;
            for (int c = 0; c < CC; c++) acc += pl[c] * w_s1[tid * CC + c];
            float h1 = fmaxf(acc * (1.f / 1024.f) + b_s1[tid], 0.f);
            gred[tid] = h1 * w_s2[tid];
        }
        __syncthreads();
        if (tid < 64) gred[tid] += gred[tid + 64];
        __syncthreads();
        if (tid == 0) {
            float sum = 0.f;
            for (int i = 0; i < 64; i++) sum += gred[i];
            gate[b2] = (sum + b_s2[0] > 0.f) ? 1.f : 0.f;
        }
        return;
    }
    int b2 = blockIdx.x >> 6; int tile = blockIdx.x & 63; int s0 = tile * 16;
    for (int i = tid; i < CC * RC; i += 256) { int r = i >> 8, c = i & 255; wredT[c * 33 + r] = w_red[i]; }
    for (int i = tid; i < 96 * RC; i += 256) { int j = i >> 5, r = i & 31; wqP[j * 33 + r] = w_qkv[i]; }
    __syncthreads();
    int s_loc = tid >> 4, p = tid & 15;
    int s = s0 + s_loc;
    float xf[RC];
    #pragma unroll
    for (int r = 0; r < RC; r++) xf[r] = 0.f;
    const float* pc = comb + (size_t)(b2 * CC) * SS + s;
    #pragma unroll
    for (int ci = 0; ci < 16; ci++) {
        int c = p + 16 * ci;
        float val = pc[(size_t)c * SS];
        #pragma unroll
        for (int r = 0; r < RC; r++) xf[r] += val * wredT[c * 33 + r];
    }
    #pragma unroll
    for (int m1 = 1; m1 <= 8; m1 <<= 1) {
        #pragma unroll
        for (int r = 0; r < RC; r++) xf[r] += __shfl_xor(xf[r], m1);
    }
    #pragma unroll
    for (int r = 0; r < RC; r++) xf[r] += b_red[r];
    size_t qbase = (size_t)(b2 * SS + s) * RC;
    #pragma unroll
    for (int jj = 0; jj < 6; jj++) {
        int j = p * 6 + jj;
        float acc = b_qkv[j];
        #pragma unroll
        for (int r = 0; r < RC; r++) acc += xf[r] * wqP[j * 33 + r];
        if      (j < 32) q[qbase + j] = acc;
        else if (j < 64) kT[((size_t)(b2 * RC + (j - 32)) << 10) + s] = acc;   // K^T [b2][r][s]
        else             vT[((size_t)(b2 * RC + (j - 64)) << 10) + s] = acc;   // V^T [b2][r][s]
    }
}

// ---------- K3: attention; 1 wave = 1 row; transposed K/V -> fully coalesced loads ----------
// col = 256*i + 4*lane + j (i=0..3 super-blocks, j=0..3 within float4). u[4i+j] = key.
__global__ __launch_bounds__(256, 2) void k_attn(
        const float* __restrict__ qg, const float* __restrict__ kT,
        const float* __restrict__ vT, float* __restrict__ mid) {
    int tid = threadIdx.x;
    int wid = tid >> 6, lane = tid & 63;
    int row = blockIdx.x * 4 + wid;               // 0..4095, same b2 within block
    int b2 = row >> 10;
    const float4* kt4 = (const float4*)(kT + ((size_t)(b2 * RC) << 10));
    const float4* vt4 = (const float4*)(vT + ((size_t)(b2 * RC) << 10));

    float qreg[RC];
    { const float4* qp = (const float4*)(qg + (size_t)row * RC);
      #pragma unroll
      for (int i = 0; i < 8; i++) { float4 t = qp[i]; qreg[4*i]=t.x; qreg[4*i+1]=t.y; qreg[4*i+2]=t.z; qreg[4*i+3]=t.w; } }

    const float scale = 0.17677669529663687f;     // 1/sqrt(32)
    // ---- QK^T: coalesced float4 streams over K^T rows ----
    float sc[4][4];
    #pragma unroll
    for (int i = 0; i < 4; i++) { sc[i][0]=0.f; sc[i][1]=0.f; sc[i][2]=0.f; sc[i][3]=0.f; }
    #pragma unroll
    for (int i = 0; i < 4; i++) {
        #pragma unroll
        for (int r = 0; r < RC; r++) {
            float4 kv = kt4[r * 256 + 64 * i + lane];   // lanes -> consecutive float4s
            float qv = qreg[r];
            sc[i][0] += qv * kv.x; sc[i][1] += qv * kv.y;
            sc[i][2] += qv * kv.z; sc[i][3] += qv * kv.w;
        }
    }
    unsigned int u[16];
    float lmax = -INFINITY;
    #pragma unroll
    for (int i = 0; i < 4; i++) {
        #pragma unroll
        for (int j = 0; j < 4; j++) {
            float d = sc[i][j] * scale;
            if (d != d) d = -INFINITY;            // NaN -> -inf per reference
            lmax = fmaxf(lmax, d);
            unsigned int bb = __float_as_uint(d);
            u[4*i+j] = bb ^ ((bb & 0x80000000u) ? 0xFFFFFFFFu : 0x80000000u);
        }
    }
    #pragma unroll
    for (int off = 32; off; off >>= 1) lmax = fmaxf(lmax, __shfl_xor(lmax, off));
    float m = lmax;

    // ---- exact top-768 threshold: bitwise binary search on uint keys ----
    unsigned int p = 0u, utau = 0u; bool found = false;
    for (int bit = 31; bit >= 0; --bit) {
        if (found) break;
        unsigned int cand = p | (1u << bit);
        int cnt = 0;
        #pragma unroll
        for (int i = 0; i < 16; i++) cnt += (u[i] >= cand) ? 1 : 0;
        #pragma unroll
        for (int off = 1; off <= 32; off <<= 1) cnt += __shfl_xor(cnt, off);
        if (cnt >= KV) {
            if (cnt == KV) {                      // tau = min key >= cand
                unsigned int um = 0xFFFFFFFFu;
                #pragma unroll
                for (int i = 0; i < 16; i++) if (u[i] >= cand && u[i] < um) um = u[i];
                #pragma unroll
                for (int off = 1; off <= 32; off <<= 1) {
                    unsigned int o = (unsigned int)__shfl_xor((int)um, off);
                    um = (o < um) ? o : um;
                }
                utau = um; found = true;
            } else p = cand;
        }
    }
    if (!found) utau = p;

    int cg = 0, eqc = 0;
    #pragma unroll
    for (int i = 0; i < 16; i++) { cg += (u[i] > utau) ? 1 : 0; eqc += (u[i] == utau) ? 1 : 0; }
    #pragma unroll
    for (int off = 1; off <= 32; off <<= 1) { cg += __shfl_xor(cg, off); eqc += __shfl_xor(eqc, off); }
    int extra = KV - cg;

    // ---- weights overwrite keys in-place ----
    float den = 0.f;
    if (extra == eqc) {                           // common: include all ties
        #pragma unroll
        for (int i = 0; i < 16; i++) {
            bool sel = (u[i] >= utau);
            unsigned int bb = u[i] ^ ((u[i] & 0x80000000u) ? 0x80000000u : 0xFFFFFFFFu);
            float wv = sel ? expf(__uint_as_float(bb) - m) : 0.f;
            den += wv; u[i] = __float_as_uint(wv);
        }
    } else {                                      // rare: partial ties, rank by lowest col
        int prior = 0;                            // col = 256*i + 4*lane + j: lex (i, lane, j)
        unsigned long long below = (1ull << lane) - 1ull;
        #pragma unroll
        for (int i = 0; i < 4; i++) {
            unsigned long long bm0 = __ballot(u[4*i+0] == utau);
            unsigned long long bm1 = __ballot(u[4*i+1] == utau);
            unsigned long long bm2 = __ballot(u[4*i+2] == utau);
            unsigned long long bm3 = __ballot(u[4*i+3] == utau);
            int baseCnt = prior + (int)(__popcll(bm0 & below) + __popcll(bm1 & below)
                                      + __popcll(bm2 & below) + __popcll(bm3 & below));
            int rk0 = baseCnt;
            int rk1 = rk0 + (int)((bm0 >> lane) & 1ull);
            int rk2 = rk1 + (int)((bm1 >> lane) & 1ull);
            int rk3 = rk2 + (int)((bm2 >> lane) & 1ull);
            int rk[4] = {rk0, rk1, rk2, rk3};
            #pragma unroll
            for (int j = 0; j < 4; j++) {
                unsigned int uu = u[4*i+j];
                bool sel = (uu > utau) || ((uu == utau) && rk[j] < extra);
                unsigned int bb = uu ^ ((uu & 0x80000000u) ? 0x80000000u : 0xFFFFFFFFu);
                float wv = sel ? expf(__uint_as_float(bb) - m) : 0.f;
                den += wv; u[4*i+j] = __float_as_uint(wv);
            }
            prior += (int)(__popcll(bm0) + __popcll(bm1) + __popcll(bm2) + __popcll(bm3));
        }
    }
    #pragma unroll
    for (int off = 1; off <= 32; off <<= 1) den += __shfl_xor(den, off);

    // ---- PV: coalesced float4 streams over V^T rows ----
    float acc[RC];
    #pragma unroll
    for (int i = 0; i < RC; i++) acc[i] = 0.f;
    #pragma unroll
    for (int i = 0; i < 4; i++) {
        float w0 = __uint_as_float(u[4*i+0]), w1 = __uint_as_float(u[4*i+1]);
        float w2 = __uint_as_float(u[4*i+2]), w3 = __uint_as_float(u[4*i+3]);
        #pragma unroll
        for (int r = 0; r < RC; r++) {
            float4 vv = vt4[r * 256 + 64 * i + lane];
            acc[r] += w0 * vv.x + w1 * vv.y + w2 * vv.z + w3 * vv.w;
        }
    }
    // ---- in-place register-halving butterfly: 32 regs x 64 lanes -> r = lane>>1 ----
    #pragma unroll
    for (int j = 0; j < 16; j++) {
        bool hi = (lane & 32) != 0;
        float keep = hi ? acc[j + 16] : acc[j];
        float send = hi ? acc[j] : acc[j + 16];
        acc[j] = keep + __shfl_xor(send, 32);
    }
    #pragma unroll
    for (int j = 0; j < 8; j++) {
        bool hi = (lane & 16) != 0;
        float keep = hi ? acc[j + 8] : acc[j];
        float send = hi ? acc[j] : acc[j + 8];
        acc[j] = keep + __shfl_xor(send, 16);
    }
    #pragma unroll
    for (int j = 0; j < 4; j++) {
        bool hi = (lane & 8) != 0;
        float keep = hi ? acc[j + 4] : acc[j];
        float send = hi ? acc[j] : acc[j + 4];
        acc[j] = keep + __shfl_xor(send, 8);
    }
    #pragma unroll
    for (int j = 0; j < 2; j++) {
        bool hi = (lane & 4) != 0;
        float keep = hi ? acc[j + 2] : acc[j];
        float send = hi ? acc[j] : acc[j + 2];
        acc[j] = keep + __shfl_xor(send, 4);
    }
    {
        bool hi = (lane & 2) != 0;
        float keep = hi ? acc[1] : acc[0];
        float send = hi ? acc[0] : acc[1];
        acc[0] = keep + __shfl_xor(send, 2);
    }
    float tot = acc[0] + __shfl_xor(acc[0], 1);   // lanes 2r,2r+1 hold sum for r=lane>>1
    if ((lane & 1) == 0) mid[(size_t)row * RC + (lane >> 1)] = tot / den;
}

// ---------- K4: projection 32->256 + fused out0 ----------
__global__ __launch_bounds__(256) void k_proj(
        const float* __restrict__ mid, const float* __restrict__ w_red,
        const float* __restrict__ comb, const float* __restrict__ gate,
        float* __restrict__ out0, float* __restrict__ attn_out) {
    int tid = threadIdx.x;
    // fused out0: 131072 float4s over 32768 threads
    #pragma unroll
    for (int j = 0; j < 4; j++) {
        int idx4 = blockIdx.x * 256 + tid + 32768 * j;
        int b = idx4 >> 16; int c = (idx4 >> 8) & 255; int s4 = idx4 & 255;
        const float4 v0 = *(const float4*)(comb + (((size_t)(b * 2 + 0) * CC + c) << 10) + s4 * 4);
        const float4 v1 = *(const float4*)(comb + (((size_t)(b * 2 + 1) * CC + c) << 10) + s4 * 4);
        float g0 = gate[b * 2 + 0], g1 = gate[b * 2 + 1];
        float4 o;
        o.x = fmaxf(g0 * v0.x, g1 * v1.x); o.y = fmaxf(g0 * v0.y, g1 * v1.y);
        o.z = fmaxf(g0 * v0.z, g1 * v1.z); o.w = fmaxf(g0 * v0.w, g1 * v1.w);
        *(float4*)(out0 + (size_t)idx4 * 4) = o;
    }
    __shared__ float wr[32 * 32];
    int b2 = blockIdx.x >> 5; int st = (blockIdx.x >> 3) & 3; int cch = blockIdx.x & 7;
    for (int i = tid; i < 1024; i += 256) {
        int rr = i >> 5, cc = i & 31;
        wr[i] = w_red[rr * CC + cch * 32 + cc];
    }
    __syncthreads();
    int s = st * 256 + tid;
    float xr[RC];
    const float4* mp = (const float4*)(mid + (size_t)(b2 * SS + s) * RC);
    #pragma unroll
    for (int i = 0; i < 8; i++) { float4 t4 = mp[i]; xr[4*i]=t4.x; xr[4*i+1]=t4.y; xr[4*i+2]=t4.z; xr[4*i+3]=t4.w; }
    #pragma unroll
    for (int cc = 0; cc < 32; cc++) {
        float a = 0.f;
        #pragma unroll
        for (int rr = 0; rr < RC; rr++) a += xr[rr] * wr[rr * 32 + cc];
        attn_out[((size_t)(b2 * CC) + cch * 32 + cc) * SS + s] = a;
    }
}

extern "C" void kernel_launch(void* const* d_in, const int* in_sizes, int n_in,
                              void* d_out, int out_size, void* d_ws, size_t ws_size,
                              hipStream_t stream) {
    const float* x     = (const float*)d_in[0];
    const float* mixp  = (const float*)d_in[1];
    const float* w_red = (const float*)d_in[2];
    const float* b_red = (const float*)d_in[3];
    const float* w_qkv = (const float*)d_in[4];
    const float* b_qkv = (const float*)d_in[5];
    const float* w_s1  = (const float*)d_in[6];
    const float* b_s1  = (const float*)d_in[7];
    const float* w_s2  = (const float*)d_in[8];
    const float* b_s2  = (const float*)d_in[9];
    float* out = (float*)d_out;

    float* ws     = (float*)d_ws;
    float* comb   = ws;                 // 1048576
    float* q      = comb + 1048576;     // 131072
    float* kT     = q + 131072;         // 131072  (K^T [b2][r][s])
    float* vT     = kT + 131072;        // 131072  (V^T [b2][r][s])
    float* mid    = vT + 131072;        // 131072
    float* pooled = mid + 131072;       // 1024
    float* gate   = pooled + 1024;      // 4

    k_pool<<<512,  256, 0, stream>>>(x, mixp, comb, pooled);
    k_qkv <<<260,  256, 0, stream>>>(comb, w_red, b_red, w_qkv, b_qkv,
                                     pooled, w_s1, b_s1, w_s2, b_s2, gate, q, kT, vT);
    k_attn<<<1024, 256, 0, stream>>>(q, kT, vT, mid);
    k_proj<<<128,  256, 0, stream>>>(mid, w_red, comb, gate, out, out + 524288);
}